// Round 3
// baseline (785.687 us; speedup 1.0000x reference)
//
#include <hip/hip_runtime.h>
#include <hip/hip_bf16.h>

typedef __attribute__((ext_vector_type(8))) short bf16x8;
typedef __attribute__((ext_vector_type(4))) float f32x4;

__device__ __forceinline__ void async16(const void* g, void* l) {
    __builtin_amdgcn_global_load_lds(
        (const __attribute__((address_space(1))) unsigned int*)g,
        (__attribute__((address_space(3))) unsigned int*)l, 16, 0, 0);
}

// ---------------------------------------------------------------------------
// pack_x: x5 (f32, [16][512][16][300]) -> X3 (bf16, [16][16][300][512]) channel-last
// grid (256 bh, 5 wt, 8 ct), block 256. float4 reads, 8B bf16x4 writes.
// ---------------------------------------------------------------------------
__global__ __launch_bounds__(256) void pack_x(const float* __restrict__ x5,
                                              __hip_bfloat16* __restrict__ X3) {
    __shared__ float tile[64][65];
    const int bh = blockIdx.x;
    const int b = bh >> 4, h = bh & 15;
    const int w0 = blockIdx.y * 64, c0 = blockIdx.z * 64;
    const int lw = (threadIdx.x & 15) * 4;
    const int lc = threadIdx.x >> 4;
#pragma unroll
    for (int i = 0; i < 4; ++i) {
        const int c = lc + i * 16;
        const int w = w0 + lw;
        const float* src = &x5[((size_t)(b * 512 + c0 + c) * 16 + h) * 300 + w];
        float4 v = {0.f, 0.f, 0.f, 0.f};
        if (w + 3 < 300) v = *(const float4*)src;
        else {
            if (w < 300)     v.x = src[0];
            if (w + 1 < 300) v.y = src[1];
            if (w + 2 < 300) v.z = src[2];
        }
        *(float4*)&tile[c][lw] = v;
    }
    __syncthreads();
    const int sc = (threadIdx.x & 15) * 4;
    const int sw0 = threadIdx.x >> 4;
#pragma unroll
    for (int i = 0; i < 4; ++i) {
        const int wl = sw0 + i * 16;
        const int w = w0 + wl;
        if (w < 300) {
            __hip_bfloat16 p[4];
            p[0] = __float2bfloat16(tile[sc + 0][wl]);
            p[1] = __float2bfloat16(tile[sc + 1][wl]);
            p[2] = __float2bfloat16(tile[sc + 2][wl]);
            p[3] = __float2bfloat16(tile[sc + 3][wl]);
            *(uint2*)&X3[(((size_t)(b * 16 + h) * 300 + w)) * 512 + c0 + sc] = *(uint2*)p;
        }
    }
}

// ---------------------------------------------------------------------------
// pack_a: coalesced via LDS transpose. Each block owns one co row (3584 floats
// contiguous in source), transposes (ci,kh)->(kh,ci) in LDS. grid 640.
// ---------------------------------------------------------------------------
__global__ __launch_bounds__(256) void pack_a(const float* __restrict__ conv_w,
                                              const float* __restrict__ cc_w,
                                              __hip_bfloat16* __restrict__ A2) {
    __shared__ float w[3584];
    const int co = blockIdx.x;
    if (co < 522) {
        const float4* src = (co < 512) ? (const float4*)(conv_w + (size_t)co * 3584)
                                       : (const float4*)(cc_w + (size_t)(co - 512) * 3584);
        for (int i = threadIdx.x; i < 896; i += 256) *(float4*)&w[i * 4] = src[i];
    } else {
        for (int i = threadIdx.x; i < 3584; i += 256) w[i] = 0.f;
    }
    __syncthreads();
    for (int kk = threadIdx.x * 4; kk < 3584; kk += 1024) {
        __hip_bfloat16 p[4];
#pragma unroll
        for (int j = 0; j < 4; ++j) {
            const int k = kk + j;
            p[j] = __float2bfloat16(w[(k & 511) * 7 + (k >> 9)]);   // stride 7: bank-conflict-free
        }
        *(uint2*)&A2[(size_t)co * 3584 + kk] = *(uint2*)p;
    }
}

// ---------------------------------------------------------------------------
// conv_gemm: implicit-im2col MFMA GEMM, XOR-swizzled LDS, single-stage
// double-buffered async prefetch: ONE barrier per K-step; the vmcnt(0) drain
// at each barrier waits on loads issued a full compute-phase earlier.
// ---------------------------------------------------------------------------
__global__ __launch_bounds__(256, 4) void conv_gemm(
    const __hip_bfloat16* __restrict__ A2, const __hip_bfloat16* __restrict__ X3,
    const float* __restrict__ conv_b, const float* __restrict__ cc_b,
    __hip_bfloat16* __restrict__ feats, float* __restrict__ scores) {
    // LDS: A buf0 [0,8K) A buf1 [8K,16K) B buf0 [16K,24K) B buf1 [24K,32K)
    __shared__ __align__(16) char lds[32768];
    const int tid = threadIdx.x;
    const int wv = tid >> 6;
    const int lane = tid & 63;
    const int m0 = blockIdx.x * 128;
    const int nt = blockIdx.y;
    const int b = blockIdx.z;

    const int row0 = wv * 16 + (lane >> 2);   // 0..63
    const int kseg = (lane & 3) ^ ((lane >> 3) & 3);   // XOR-swizzled source segment

    const char* gA0 = (const char*)A2 + (size_t)(m0 + row0) * 7168 + (size_t)kseg * 16;
    const char* gA1 = gA0 + (size_t)64 * 7168;

    int n0 = nt * 128 + row0;      if (n0 > 2999) n0 = 2999;
    int n1 = nt * 128 + row0 + 64; if (n1 > 2999) n1 = 2999;
    const char* gB0 = (const char*)X3 + ((size_t)((b * 16 + n0 / 300) * 300 + n0 % 300)) * 1024 + (size_t)kseg * 16;
    const char* gB1 = (const char*)X3 + ((size_t)((b * 16 + n1 / 300) * 300 + n1 % 300)) * 1024 + (size_t)kseg * 16;

    char* lA = lds + wv * 1024 + lane * 16;           // +4096: rows 64..127
    char* lB = lds + 16384 + wv * 1024 + lane * 16;

    const int wm = (wv & 1) * 64;
    const int wn = (wv >> 1) * 64;
    const int fl = lane & 15;
    const int sq = lane >> 4;
    int aoff[4], boff[4];
#pragma unroll
    for (int i = 0; i < 4; ++i) {
        const int swz = (sq ^ ((fl >> 1) & 3)) * 16;
        aoff[i] = (wm + i * 16 + fl) * 64 + swz;
        boff[i] = 16384 + (wn + i * 16 + fl) * 64 + swz;
    }

    f32x4 acc[4][4] = {};

#define ISSUE(kt, ph)                                                                  \
    {                                                                                  \
        const size_t aadd = (size_t)(kt) * 64;                                         \
        const size_t badd = (size_t)((kt) >> 4) * 307200 + (size_t)((kt) & 15) * 64;   \
        async16(gA0 + aadd, lA + (ph) * 8192);                                         \
        async16(gA1 + aadd, lA + (ph) * 8192 + 4096);                                  \
        async16(gB0 + badd, lB + (ph) * 8192);                                         \
        async16(gB1 + badd, lB + (ph) * 8192 + 4096);                                  \
    }

#define COMPUTE(ph)                                                                    \
    {                                                                                  \
        bf16x8 af[4];                                                                  \
        _Pragma("unroll")                                                              \
        for (int mi = 0; mi < 4; ++mi)                                                 \
            af[mi] = *(const bf16x8*)(lds + (ph) * 8192 + aoff[mi]);                   \
        _Pragma("unroll")                                                              \
        for (int ni = 0; ni < 4; ++ni) {                                               \
            const bf16x8 bv = *(const bf16x8*)(lds + (ph) * 8192 + boff[ni]);          \
            _Pragma("unroll")                                                          \
            for (int mi = 0; mi < 4; ++mi)                                             \
                acc[mi][ni] = __builtin_amdgcn_mfma_f32_16x16x32_bf16(af[mi], bv, acc[mi][ni], 0, 0, 0); \
        }                                                                              \
    }

    ISSUE(0, 0);
    for (int kt = 0; kt < 112; kt += 2) {
        __syncthreads();              // drains prefetch(kt) -> buf0 ready; buf1 reads of kt-1 done
        ISSUE(kt + 1, 1);
        COMPUTE(0);
        __syncthreads();              // drains prefetch(kt+1) -> buf1 ready; buf0 reads done
        if (kt < 110) ISSUE(kt + 2, 0);
        COMPUTE(1);
    }
#undef ISSUE
#undef COMPUTE

    const int quad4 = (lane >> 4) * 4;
#pragma unroll
    for (int ni = 0; ni < 4; ++ni) {
        const int n = nt * 128 + wn + ni * 16 + fl;
        if (n >= 3000) continue;
#pragma unroll
        for (int mi = 0; mi < 4; ++mi) {
            const int cob = m0 + wm + mi * 16 + quad4;
            const f32x4 v = acc[mi][ni];
#pragma unroll
            for (int r = 0; r < 4; ++r) {
                const int co = cob + r;
                float val = v[r];
                if (co < 512) {
                    val = fmaxf(val + conv_b[co], 0.f);
                    feats[(size_t)(b * 512 + co) * 3000 + n] = __float2bfloat16(val);
                } else if (co < 522) {
                    scores[(size_t)(b * 10 + (co - 512)) * 3000 + n] = val + cc_b[co - 512];
                }
            }
        }
    }
}

// ---------------------------------------------------------------------------
// softmax over k=10 (in-place scores->assign) + asum via atomics. grid (16,12)
// ---------------------------------------------------------------------------
__global__ __launch_bounds__(256) void softmax_assign(float* __restrict__ scores,
                                                      float* __restrict__ asum) {
    const int b = blockIdx.x;
    const int hw = blockIdx.y * 256 + threadIdx.x;
    const bool valid = hw < 3000;
    float part[10];
    if (valid) {
        float s[10], mx = -1e30f;
#pragma unroll
        for (int k = 0; k < 10; ++k) { s[k] = scores[(size_t)(b * 10 + k) * 3000 + hw]; mx = fmaxf(mx, s[k]); }
        float sum = 0.f;
#pragma unroll
        for (int k = 0; k < 10; ++k) { part[k] = __expf(s[k] - mx); sum += part[k]; }
        const float inv = 1.f / sum;
#pragma unroll
        for (int k = 0; k < 10; ++k) {
            part[k] *= inv;
            scores[(size_t)(b * 10 + k) * 3000 + hw] = part[k];
        }
    } else {
#pragma unroll
        for (int k = 0; k < 10; ++k) part[k] = 0.f;
    }
    __shared__ float red[4][10];
    const int lane = threadIdx.x & 63, w = threadIdx.x >> 6;
#pragma unroll
    for (int k = 0; k < 10; ++k) {
        float v = part[k];
        for (int off = 32; off; off >>= 1) v += __shfl_xor(v, off, 64);
        if (lane == 0) red[w][k] = v;
    }
    __syncthreads();
    if (threadIdx.x < 10)
        atomicAdd(&asum[b * 10 + threadIdx.x],
                  red[0][threadIdx.x] + red[1][threadIdx.x] + red[2][threadIdx.x] + red[3][threadIdx.x]);
}

// ---------------------------------------------------------------------------
// agg[b][k][c] = sum_hw assign[b][k][hw] * feats[b][c][hw]. grid (512 c, 16 b)
// ---------------------------------------------------------------------------
__global__ __launch_bounds__(256) void agg_kernel(const __hip_bfloat16* __restrict__ feats,
                                                  const float* __restrict__ assign,
                                                  float* __restrict__ agg) {
    const int c = blockIdx.x, b = blockIdx.y;
    const __hip_bfloat16* fp = feats + (size_t)(b * 512 + c) * 3000;
    float acc[10];
#pragma unroll
    for (int k = 0; k < 10; ++k) acc[k] = 0.f;
    for (int p = threadIdx.x; p < 1500; p += 256) {
        const int hw = p * 2;
        const __hip_bfloat162 f2 = *(const __hip_bfloat162*)&fp[hw];
        const float f0 = __bfloat162float(f2.x), f1 = __bfloat162float(f2.y);
#pragma unroll
        for (int k = 0; k < 10; ++k) {
            const float2 a2 = *(const float2*)&assign[(size_t)(b * 10 + k) * 3000 + hw];
            acc[k] += a2.x * f0 + a2.y * f1;
        }
    }
    __shared__ float red[4][10];
    const int lane = threadIdx.x & 63, w = threadIdx.x >> 6;
#pragma unroll
    for (int k = 0; k < 10; ++k) {
        float v = acc[k];
        for (int off = 32; off; off >>= 1) v += __shfl_xor(v, off, 64);
        if (lane == 0) red[w][k] = v;
    }
    __syncthreads();
    if (threadIdx.x < 10)
        agg[(size_t)(b * 10 + threadIdx.x) * 512 + c] =
            red[0][threadIdx.x] + red[1][threadIdx.x] + red[2][threadIdx.x] + red[3][threadIdx.x];
}

// ---------------------------------------------------------------------------
// vlad: cluster_res = agg - asum*centroid, L2-normalize per (b,k<8). grid (8,16)
// ---------------------------------------------------------------------------
__global__ __launch_bounds__(256) void vlad_kernel(const float* __restrict__ agg,
                                                   const float* __restrict__ asum,
                                                   const float* __restrict__ centroids,
                                                   float* __restrict__ vlad) {
    const int k = blockIdx.x, b = blockIdx.y;
    const int t = threadIdx.x;
    const float av = asum[b * 10 + k];
    const float r0 = agg[(size_t)(b * 10 + k) * 512 + t]       - av * centroids[k * 512 + t];
    const float r1 = agg[(size_t)(b * 10 + k) * 512 + t + 256] - av * centroids[k * 512 + t + 256];
    float v = r0 * r0 + r1 * r1;
    __shared__ float red[4];
    __shared__ float sscale;
    const int lane = t & 63, w = t >> 6;
    for (int off = 32; off; off >>= 1) v += __shfl_xor(v, off, 64);
    if (lane == 0) red[w] = v;
    __syncthreads();
    if (t == 0) {
        const float nrm = sqrtf(red[0] + red[1] + red[2] + red[3]);
        sscale = 1.f / fmaxf(nrm, 1e-12f);
    }
    __syncthreads();
    const float sc = sscale;
    vlad[(size_t)b * 4096 + k * 512 + t] = r0 * sc;
    vlad[(size_t)b * 4096 + k * 512 + t + 256] = r1 * sc;
}

// ---------------------------------------------------------------------------
// fc: emb = relu(vlad @ fc_w.T + fc_b) -> out[0:8192]. grid (16,16), block 256.
// ---------------------------------------------------------------------------
__global__ __launch_bounds__(256) void fc_kernel(const float* __restrict__ vlad,
                                                 const float* __restrict__ fc_w,
                                                 const float* __restrict__ fc_b,
                                                 float* __restrict__ out) {
    const int b = blockIdx.y;
    const int col = threadIdx.x >> 3;
    const int ks = threadIdx.x & 7;
    const int co = blockIdx.x * 32 + col;
    const float4* v4 = (const float4*)(vlad + (size_t)b * 4096);
    const float4* w4 = (const float4*)(fc_w + (size_t)co * 4096);
    float acc = 0.f;
    for (int i = ks; i < 1024; i += 8) {
        const float4 a = v4[i], w = w4[i];
        acc += a.x * w.x + a.y * w.y + a.z * w.z + a.w * w.w;
    }
    acc += __shfl_down(acc, 4, 8);
    acc += __shfl_down(acc, 2, 8);
    acc += __shfl_down(acc, 1, 8);
    if (ks == 0) out[b * 512 + co] = fmaxf(acc + fc_b[co], 0.f);
}

// ---------------------------------------------------------------------------
// logit: out[8192 + b*5994 + o] = emb[b].logit_w[o]. grid (16 b, 24 o-tiles).
// ---------------------------------------------------------------------------
__global__ __launch_bounds__(256) void logit_kernel(const float* __restrict__ emb,
                                                    const float* __restrict__ logit_w,
                                                    float* __restrict__ out) {
    __shared__ float se[512];
    const int b = blockIdx.x;
    se[threadIdx.x] = emb[b * 512 + threadIdx.x];
    se[threadIdx.x + 256] = emb[b * 512 + threadIdx.x + 256];
    __syncthreads();
    const int o = blockIdx.y * 256 + threadIdx.x;
    if (o < 5994) {
        const float4* w4 = (const float4*)(logit_w + (size_t)o * 512);
        float acc = 0.f;
        for (int i = 0; i < 128; ++i) {
            const float4 w = w4[i];
            acc += w.x * se[4 * i] + w.y * se[4 * i + 1] + w.z * se[4 * i + 2] + w.w * se[4 * i + 3];
        }
        out[8192 + b * 5994 + o] = acc;
    }
}

extern "C" void kernel_launch(void* const* d_in, const int* in_sizes, int n_in,
                              void* d_out, int out_size, void* d_ws, size_t ws_size,
                              hipStream_t stream) {
    (void)in_sizes; (void)n_in; (void)out_size; (void)ws_size;
    const float* x5       = (const float*)d_in[0];
    const float* conv_w   = (const float*)d_in[5];
    const float* conv_b   = (const float*)d_in[6];
    const float* cc_w     = (const float*)d_in[7];
    const float* cc_b     = (const float*)d_in[8];
    const float* centroids= (const float*)d_in[9];
    const float* fc_w     = (const float*)d_in[10];
    const float* fc_b     = (const float*)d_in[11];
    const float* logit_w  = (const float*)d_in[12];
    float* out = (float*)d_out;

    char* ws = (char*)d_ws;
    __hip_bfloat16* X3    = (__hip_bfloat16*)(ws);              // 78,643,200 B
    __hip_bfloat16* A2    = (__hip_bfloat16*)(ws + 78643200);   //  4,587,520 B
    __hip_bfloat16* feats = (__hip_bfloat16*)(ws + 83230720);   // 49,152,000 B
    float* scores         = (float*)(ws + 132382720);           //  1,920,000 B
    float* asum           = (float*)(ws + 134302720);           //        640 B
    float* agg            = (float*)(ws + 134303360);           //    327,680 B
    float* vlad           = (float*)(ws + 134631040);           //    262,144 B

    hipMemsetAsync(asum, 0, 640, stream);
    pack_x<<<dim3(256, 5, 8), 256, 0, stream>>>(x5, X3);
    pack_a<<<dim3(640), 256, 0, stream>>>(conv_w, cc_w, A2);
    conv_gemm<<<dim3(5, 24, 16), 256, 0, stream>>>(A2, X3, conv_b, cc_b, feats, scores);
    softmax_assign<<<dim3(16, 12), 256, 0, stream>>>(scores, asum);
    agg_kernel<<<dim3(512, 16), 256, 0, stream>>>(feats, scores, agg);
    vlad_kernel<<<dim3(8, 16), 256, 0, stream>>>(agg, asum, centroids, vlad);
    fc_kernel<<<dim3(16, 16), 256, 0, stream>>>(vlad, fc_w, fc_b, out);
    logit_kernel<<<dim3(16, 24), 256, 0, stream>>>(out, logit_w, out);
}

// Round 4
// 681.304 us; speedup vs baseline: 1.1532x; 1.1532x over previous
//
#include <hip/hip_runtime.h>
#include <hip/hip_bf16.h>

typedef __attribute__((ext_vector_type(8))) short bf16x8;
typedef __attribute__((ext_vector_type(4))) float f32x4;

__device__ __forceinline__ void async16(const void* g, void* l) {
    __builtin_amdgcn_global_load_lds(
        (const __attribute__((address_space(1))) unsigned int*)g,
        (__attribute__((address_space(3))) unsigned int*)l, 16, 0, 0);
}

// ---------------------------------------------------------------------------
// pack_x: x5 (f32, [16][512][16][300]) -> X3 (bf16, [16][16][300][512]) channel-last
// ---------------------------------------------------------------------------
__global__ __launch_bounds__(256) void pack_x(const float* __restrict__ x5,
                                              __hip_bfloat16* __restrict__ X3) {
    __shared__ float tile[64][65];
    const int bh = blockIdx.x;
    const int b = bh >> 4, h = bh & 15;
    const int w0 = blockIdx.y * 64, c0 = blockIdx.z * 64;
    const int lw = (threadIdx.x & 15) * 4;
    const int lc = threadIdx.x >> 4;
#pragma unroll
    for (int i = 0; i < 4; ++i) {
        const int c = lc + i * 16;
        const int w = w0 + lw;
        const float* src = &x5[((size_t)(b * 512 + c0 + c) * 16 + h) * 300 + w];
        float4 v = {0.f, 0.f, 0.f, 0.f};
        if (w + 3 < 300) v = *(const float4*)src;
        else {
            if (w < 300)     v.x = src[0];
            if (w + 1 < 300) v.y = src[1];
            if (w + 2 < 300) v.z = src[2];
        }
        *(float4*)&tile[c][lw] = v;
    }
    __syncthreads();
    const int sc = (threadIdx.x & 15) * 4;
    const int sw0 = threadIdx.x >> 4;
#pragma unroll
    for (int i = 0; i < 4; ++i) {
        const int wl = sw0 + i * 16;
        const int w = w0 + wl;
        if (w < 300) {
            __hip_bfloat16 p[4];
            p[0] = __float2bfloat16(tile[sc + 0][wl]);
            p[1] = __float2bfloat16(tile[sc + 1][wl]);
            p[2] = __float2bfloat16(tile[sc + 2][wl]);
            p[3] = __float2bfloat16(tile[sc + 3][wl]);
            *(uint2*)&X3[(((size_t)(b * 16 + h) * 300 + w)) * 512 + c0 + sc] = *(uint2*)p;
        }
    }
}

// ---------------------------------------------------------------------------
// pack_a: coalesced via LDS transpose. grid 640.
// ---------------------------------------------------------------------------
__global__ __launch_bounds__(256) void pack_a(const float* __restrict__ conv_w,
                                              const float* __restrict__ cc_w,
                                              __hip_bfloat16* __restrict__ A2) {
    __shared__ float w[3584];
    const int co = blockIdx.x;
    if (co < 522) {
        const float4* src = (co < 512) ? (const float4*)(conv_w + (size_t)co * 3584)
                                       : (const float4*)(cc_w + (size_t)(co - 512) * 3584);
        for (int i = threadIdx.x; i < 896; i += 256) *(float4*)&w[i * 4] = src[i];
    } else {
        for (int i = threadIdx.x; i < 3584; i += 256) w[i] = 0.f;
    }
    __syncthreads();
    for (int kk = threadIdx.x * 4; kk < 3584; kk += 1024) {
        __hip_bfloat16 p[4];
#pragma unroll
        for (int j = 0; j < 4; ++j) {
            const int k = kk + j;
            p[j] = __float2bfloat16(w[(k & 511) * 7 + (k >> 9)]);
        }
        *(uint2*)&A2[(size_t)co * 3584 + kk] = *(uint2*)p;
    }
}

// ---------------------------------------------------------------------------
// conv_gemm: implicit-im2col MFMA GEMM, XOR-swizzled LDS, double-buffered
// prefetch, XCD-aware work remap: gid&7 selects XCD (HW round-robin); each
// XCD owns 48 (nt,b) tiles x 5 m-tiles so all 35x reuse of every X3 byte
// (5 m-tiles x 7 kh) stays inside ONE XCD's 4MB L2.
// feats written channel-last: [b][n][co] bf16.
// ---------------------------------------------------------------------------
__global__ __launch_bounds__(256, 4) void conv_gemm(
    const __hip_bfloat16* __restrict__ A2, const __hip_bfloat16* __restrict__ X3,
    const float* __restrict__ conv_b, const float* __restrict__ cc_b,
    __hip_bfloat16* __restrict__ feats, float* __restrict__ scores) {
    __shared__ __align__(16) char lds[32768];
    const int tid = threadIdx.x;
    const int wv = tid >> 6;
    const int lane = tid & 63;

    // XCD-aware remap (1920 blocks = 8 XCD * 48 (nt,b) * 5 m)
    const int gid = blockIdx.x;
    const int xcd = gid & 7;
    const int j = gid >> 3;            // 0..239
    const int nb = xcd * 48 + j / 5;   // 0..383 ; nb = b*24 + nt
    const int m0 = (j % 5) * 128;
    const int b = nb / 24;
    const int nt = nb % 24;

    const int row0 = wv * 16 + (lane >> 2);            // 0..63
    const int kseg = (lane & 3) ^ ((lane >> 3) & 3);   // XOR-swizzled source segment

    const char* gA0 = (const char*)A2 + (size_t)(m0 + row0) * 7168 + (size_t)kseg * 16;
    const char* gA1 = gA0 + (size_t)64 * 7168;

    int n0 = nt * 128 + row0;      if (n0 > 2999) n0 = 2999;
    int n1 = nt * 128 + row0 + 64; if (n1 > 2999) n1 = 2999;
    const char* gB0 = (const char*)X3 + ((size_t)((b * 16 + n0 / 300) * 300 + n0 % 300)) * 1024 + (size_t)kseg * 16;
    const char* gB1 = (const char*)X3 + ((size_t)((b * 16 + n1 / 300) * 300 + n1 % 300)) * 1024 + (size_t)kseg * 16;

    char* lA = lds + wv * 1024 + lane * 16;
    char* lB = lds + 16384 + wv * 1024 + lane * 16;

    const int wm = (wv & 1) * 64;
    const int wn = (wv >> 1) * 64;
    const int fl = lane & 15;
    const int sq = lane >> 4;
    int aoff[4], boff[4];
#pragma unroll
    for (int i = 0; i < 4; ++i) {
        const int swz = (sq ^ ((fl >> 1) & 3)) * 16;
        aoff[i] = (wm + i * 16 + fl) * 64 + swz;
        boff[i] = 16384 + (wn + i * 16 + fl) * 64 + swz;
    }

    f32x4 acc[4][4] = {};

#define ISSUE(kt, ph)                                                                  \
    {                                                                                  \
        const size_t aadd = (size_t)(kt) * 64;                                         \
        const size_t badd = (size_t)((kt) >> 4) * 307200 + (size_t)((kt) & 15) * 64;   \
        async16(gA0 + aadd, lA + (ph) * 8192);                                         \
        async16(gA1 + aadd, lA + (ph) * 8192 + 4096);                                  \
        async16(gB0 + badd, lB + (ph) * 8192);                                         \
        async16(gB1 + badd, lB + (ph) * 8192 + 4096);                                  \
    }

#define COMPUTE(ph)                                                                    \
    {                                                                                  \
        bf16x8 af[4];                                                                  \
        _Pragma("unroll")                                                              \
        for (int mi = 0; mi < 4; ++mi)                                                 \
            af[mi] = *(const bf16x8*)(lds + (ph) * 8192 + aoff[mi]);                   \
        _Pragma("unroll")                                                              \
        for (int ni = 0; ni < 4; ++ni) {                                               \
            const bf16x8 bv = *(const bf16x8*)(lds + (ph) * 8192 + boff[ni]);          \
            _Pragma("unroll")                                                          \
            for (int mi = 0; mi < 4; ++mi)                                             \
                acc[mi][ni] = __builtin_amdgcn_mfma_f32_16x16x32_bf16(af[mi], bv, acc[mi][ni], 0, 0, 0); \
        }                                                                              \
    }

    ISSUE(0, 0);
    for (int kt = 0; kt < 112; kt += 2) {
        __syncthreads();
        ISSUE(kt + 1, 1);
        COMPUTE(0);
        __syncthreads();
        if (kt < 110) ISSUE(kt + 2, 0);
        COMPUTE(1);
    }
#undef ISSUE
#undef COMPUTE

    const int quad4 = (lane >> 4) * 4;
#pragma unroll
    for (int ni = 0; ni < 4; ++ni) {
        const int n = nt * 128 + wn + ni * 16 + fl;
        if (n >= 3000) continue;
#pragma unroll
        for (int mi = 0; mi < 4; ++mi) {
            const int cob = m0 + wm + mi * 16 + quad4;
            const f32x4 v = acc[mi][ni];
            if (cob < 512) {
                __hip_bfloat16 p[4];
#pragma unroll
                for (int r = 0; r < 4; ++r)
                    p[r] = __float2bfloat16(fmaxf(v[r] + conv_b[cob + r], 0.f));
                *(uint2*)&feats[((size_t)(b * 3000 + n)) * 512 + cob] = *(uint2*)p;
            } else {
#pragma unroll
                for (int r = 0; r < 4; ++r) {
                    const int co = cob + r;
                    if (co < 522)
                        scores[(size_t)(b * 10 + (co - 512)) * 3000 + n] = v[r] + cc_b[co - 512];
                }
            }
        }
    }
}

// ---------------------------------------------------------------------------
// softmax over k=10 (in-place scores->assign) + asum via atomics. grid (16,12)
// ---------------------------------------------------------------------------
__global__ __launch_bounds__(256) void softmax_assign(float* __restrict__ scores,
                                                      float* __restrict__ asum) {
    const int b = blockIdx.x;
    const int hw = blockIdx.y * 256 + threadIdx.x;
    const bool valid = hw < 3000;
    float part[10];
    if (valid) {
        float s[10], mx = -1e30f;
#pragma unroll
        for (int k = 0; k < 10; ++k) { s[k] = scores[(size_t)(b * 10 + k) * 3000 + hw]; mx = fmaxf(mx, s[k]); }
        float sum = 0.f;
#pragma unroll
        for (int k = 0; k < 10; ++k) { part[k] = __expf(s[k] - mx); sum += part[k]; }
        const float inv = 1.f / sum;
#pragma unroll
        for (int k = 0; k < 10; ++k) {
            part[k] *= inv;
            scores[(size_t)(b * 10 + k) * 3000 + hw] = part[k];
        }
    } else {
#pragma unroll
        for (int k = 0; k < 10; ++k) part[k] = 0.f;
    }
    __shared__ float red[4][10];
    const int lane = threadIdx.x & 63, w = threadIdx.x >> 6;
#pragma unroll
    for (int k = 0; k < 10; ++k) {
        float v = part[k];
        for (int off = 32; off; off >>= 1) v += __shfl_xor(v, off, 64);
        if (lane == 0) red[w][k] = v;
    }
    __syncthreads();
    if (threadIdx.x < 10)
        atomicAdd(&asum[b * 10 + threadIdx.x],
                  red[0][threadIdx.x] + red[1][threadIdx.x] + red[2][threadIdx.x] + red[3][threadIdx.x]);
}

// ---------------------------------------------------------------------------
// agg[b][k][c] += sum_hw assign[b][k][hw] * feats[b][hw][c].
// feats channel-last: thread owns 2 channels (coalesced bf16x2), assign loads
// are block-uniform (scalarized). grid (12 hw-chunks, 16 b). agg pre-zeroed.
// ---------------------------------------------------------------------------
__global__ __launch_bounds__(256) void agg_kernel(const __hip_bfloat16* __restrict__ feats,
                                                  const float* __restrict__ assign,
                                                  float* __restrict__ agg) {
    const int chunk = blockIdx.x, b = blockIdx.y;
    const int c = threadIdx.x * 2;
    float acc0[10], acc1[10];
#pragma unroll
    for (int k = 0; k < 10; ++k) { acc0[k] = 0.f; acc1[k] = 0.f; }
    const int hw0 = chunk * 250;
    for (int i = 0; i < 250; ++i) {
        const int hw = hw0 + i;
        const __hip_bfloat162 f2 = *(const __hip_bfloat162*)&feats[((size_t)(b * 3000 + hw)) * 512 + c];
        const float f0 = __bfloat162float(f2.x), f1 = __bfloat162float(f2.y);
#pragma unroll
        for (int k = 0; k < 10; ++k) {
            const float a = assign[(size_t)(b * 10 + k) * 3000 + hw];
            acc0[k] += a * f0;
            acc1[k] += a * f1;
        }
    }
#pragma unroll
    for (int k = 0; k < 10; ++k) {
        atomicAdd(&agg[(size_t)(b * 10 + k) * 512 + c], acc0[k]);
        atomicAdd(&agg[(size_t)(b * 10 + k) * 512 + c + 1], acc1[k]);
    }
}

// ---------------------------------------------------------------------------
// vlad: cluster_res = agg - asum*centroid, L2-normalize per (b,k<8). grid (8,16)
// ---------------------------------------------------------------------------
__global__ __launch_bounds__(256) void vlad_kernel(const float* __restrict__ agg,
                                                   const float* __restrict__ asum,
                                                   const float* __restrict__ centroids,
                                                   float* __restrict__ vlad) {
    const int k = blockIdx.x, b = blockIdx.y;
    const int t = threadIdx.x;
    const float av = asum[b * 10 + k];
    const float r0 = agg[(size_t)(b * 10 + k) * 512 + t]       - av * centroids[k * 512 + t];
    const float r1 = agg[(size_t)(b * 10 + k) * 512 + t + 256] - av * centroids[k * 512 + t + 256];
    float v = r0 * r0 + r1 * r1;
    __shared__ float red[4];
    __shared__ float sscale;
    const int lane = t & 63, w = t >> 6;
    for (int off = 32; off; off >>= 1) v += __shfl_xor(v, off, 64);
    if (lane == 0) red[w] = v;
    __syncthreads();
    if (t == 0) {
        const float nrm = sqrtf(red[0] + red[1] + red[2] + red[3]);
        sscale = 1.f / fmaxf(nrm, 1e-12f);
    }
    __syncthreads();
    const float sc = sscale;
    vlad[(size_t)b * 4096 + k * 512 + t] = r0 * sc;
    vlad[(size_t)b * 4096 + k * 512 + t + 256] = r1 * sc;
}

// ---------------------------------------------------------------------------
// fc: emb = relu(vlad @ fc_w.T + fc_b) -> out[0:8192]. grid (16,16), block 256.
// ---------------------------------------------------------------------------
__global__ __launch_bounds__(256) void fc_kernel(const float* __restrict__ vlad,
                                                 const float* __restrict__ fc_w,
                                                 const float* __restrict__ fc_b,
                                                 float* __restrict__ out) {
    const int b = blockIdx.y;
    const int col = threadIdx.x >> 3;
    const int ks = threadIdx.x & 7;
    const int co = blockIdx.x * 32 + col;
    const float4* v4 = (const float4*)(vlad + (size_t)b * 4096);
    const float4* w4 = (const float4*)(fc_w + (size_t)co * 4096);
    float acc = 0.f;
    for (int i = ks; i < 1024; i += 8) {
        const float4 a = v4[i], w = w4[i];
        acc += a.x * w.x + a.y * w.y + a.z * w.z + a.w * w.w;
    }
    acc += __shfl_down(acc, 4, 8);
    acc += __shfl_down(acc, 2, 8);
    acc += __shfl_down(acc, 1, 8);
    if (ks == 0) out[b * 512 + co] = fmaxf(acc + fc_b[co], 0.f);
}

// ---------------------------------------------------------------------------
// logit: XCD-grouped — gid&7 = XCD, each XCD owns 3 o-tiles; the 16 b-blocks
// sharing one 512KB weight tile run on the same XCD (L2-hot). grid 384.
// ---------------------------------------------------------------------------
__global__ __launch_bounds__(256) void logit_kernel(const float* __restrict__ emb,
                                                    const float* __restrict__ logit_w,
                                                    float* __restrict__ out) {
    __shared__ float se[512];
    const int gid = blockIdx.x;
    const int xcd = gid & 7;
    const int j = gid >> 3;          // 0..47
    const int otile = xcd * 3 + (j >> 4);
    const int b = j & 15;
    se[threadIdx.x] = emb[b * 512 + threadIdx.x];
    se[threadIdx.x + 256] = emb[b * 512 + threadIdx.x + 256];
    __syncthreads();
    const int o = otile * 256 + threadIdx.x;
    if (o < 5994) {
        const float4* w4 = (const float4*)(logit_w + (size_t)o * 512);
        float acc = 0.f;
        for (int i = 0; i < 128; ++i) {
            const float4 w = w4[i];
            acc += w.x * se[4 * i] + w.y * se[4 * i + 1] + w.z * se[4 * i + 2] + w.w * se[4 * i + 3];
        }
        out[8192 + b * 5994 + o] = acc;
    }
}

extern "C" void kernel_launch(void* const* d_in, const int* in_sizes, int n_in,
                              void* d_out, int out_size, void* d_ws, size_t ws_size,
                              hipStream_t stream) {
    (void)in_sizes; (void)n_in; (void)out_size; (void)ws_size;
    const float* x5       = (const float*)d_in[0];
    const float* conv_w   = (const float*)d_in[5];
    const float* conv_b   = (const float*)d_in[6];
    const float* cc_w     = (const float*)d_in[7];
    const float* cc_b     = (const float*)d_in[8];
    const float* centroids= (const float*)d_in[9];
    const float* fc_w     = (const float*)d_in[10];
    const float* fc_b     = (const float*)d_in[11];
    const float* logit_w  = (const float*)d_in[12];
    float* out = (float*)d_out;

    char* ws = (char*)d_ws;
    __hip_bfloat16* X3    = (__hip_bfloat16*)(ws);              // 78,643,200 B
    __hip_bfloat16* A2    = (__hip_bfloat16*)(ws + 78643200);   //  4,587,520 B
    __hip_bfloat16* feats = (__hip_bfloat16*)(ws + 83230720);   // 49,152,000 B (channel-last)
    float* scores         = (float*)(ws + 132382720);           //  1,920,000 B
    float* asum           = (float*)(ws + 134302720);           //        640 B
    float* agg            = (float*)(ws + 134303360);           //    327,680 B (adjacent to asum)
    float* vlad           = (float*)(ws + 134631040);           //    262,144 B

    hipMemsetAsync(asum, 0, 640 + 327680, stream);   // zero asum + agg in one call
    pack_x<<<dim3(256, 5, 8), 256, 0, stream>>>(x5, X3);
    pack_a<<<dim3(640), 256, 0, stream>>>(conv_w, cc_w, A2);
    conv_gemm<<<dim3(1920), 256, 0, stream>>>(A2, X3, conv_b, cc_b, feats, scores);
    softmax_assign<<<dim3(16, 12), 256, 0, stream>>>(scores, asum);
    agg_kernel<<<dim3(12, 16), 256, 0, stream>>>(feats, scores, agg);
    vlad_kernel<<<dim3(8, 16), 256, 0, stream>>>(agg, asum, centroids, vlad);
    fc_kernel<<<dim3(16, 16), 256, 0, stream>>>(vlad, fc_w, fc_b, out);
    logit_kernel<<<dim3(384), 256, 0, stream>>>(out, logit_w, out);
}